// Round 6
// baseline (164.611 us; speedup 1.0000x reference)
//
#include <hip/hip_runtime.h>
#include <stdint.h>

// LinearAttention fused: qkv GEMM + dual softmax + linear attention + Wout GEMM + LayerNorm2d
// Shapes: b=32, c=128, n=64*64=4096, heads=4, dim_head=32.
// All GEMMs via v_mfma_f32_16x16x32_bf16 (fp32 accum).
//
// R5: k1 rebuilt: 1024-thr blocks, 16 waves, wq frags persistent in VGPRs. 181us total.
// R6: algebraic fold y = (Wout @ blockdiag_h(ctxN)) @ qsm = Wbig[b] @ qsm.
// R7: Wbig frag-major + k3 LDS-staged inner loop; k2 split. 159.9us (-17.8).
// R8: k3 256-thr TLP: NEUTRAL. R9: k3 persistent + k1 T14 split: ~NEUTRAL.
// R10: k1 single-barrier merge REGRESSED (161.4; k1 visible at 43.1us, occ 9%, all
//      pipes idle). Diagnosis: __syncthreads drains vmcnt(0) per wave, so the staged
//      x-loads issued just before the barrier stall ALL 16 waves at FULL HBM latency,
//      every phase, with 1 block/CU and nothing else to run.
// R11: block-level TLP instead of sync tricks. k1 reverted to 2-barrier/single-ekv
//      structure (LDS 71.7KB <= 80KB) and split: TPB_ 8->16, NSUB 8->4 -> grid 512
//      = 2 blocks/CU (32 waves, VGPR 64). Block B computes while block A drains.
//      ctx partials -> 16/batch (8MB); Wbig now ALIASES dead ctx_part (k2b runs
//      after k2a) keeping workspace at the proven 42,598,400-byte high-water mark.

constexpr int B_   = 32;
constexpr int C_   = 128;
constexpr int N_   = 4096;
constexpr int O3_  = 384;   // 3*128 qkv rows
constexpr int NSUB = 4;     // 64-wide n-subtiles per k1 block
constexpr int TPB_ = 16;    // k1 blocks per batch (4096 / 256)

using short8  = __attribute__((ext_vector_type(8))) short;
using short4v = __attribute__((ext_vector_type(4))) short;
using float4v = __attribute__((ext_vector_type(4))) float;

__device__ __forceinline__ unsigned short bf16_rne(float f) {
    union { float f; uint32_t u; } v; v.f = f;
    uint32_t u = v.u;
    u += 0x7FFFu + ((u >> 16) & 1u);   // round-to-nearest-even
    return (unsigned short)(u >> 16);
}
__device__ __forceinline__ float bf2f(unsigned short h) {
    union { uint32_t u; float f; } v; v.u = ((uint32_t)h) << 16; return v.f;
}

// workspace layout (bytes) -- total 42,598,400 (proven cap from R0)
constexpr size_t OFF_WQ   = 0;          // Wqkv bf16: 384*128*2 = 98304
constexpr size_t OFF_WO   = 98304;      // Wout bf16: 32768 -> 131072
constexpr size_t OFF_SP   = 131072;     // S partials [b][16][128] f32: 262144 -> 393216
constexpr size_t OFF_CTXP = 393216;     // ctx partials [b][16][4096] f32: 8388608 -> 8781824
constexpr size_t OFF_WBIG = 393216;     // Wbig bf16 TILED: 1048576 -- ALIASES dead ctx_part
constexpr size_t OFF_CTXN = 8781824;    // ctxN bf16 [b][hd][e]: 262144 -> 9043968
constexpr size_t OFF_QSM  = 9043968;    // q-softmax bf16 [b][n][h*32+d]: 33554432 -> 42598400

__global__ __launch_bounds__(256) void k0_prep(const float* __restrict__ Wqkv,
                                               const float* __restrict__ Wout,
                                               unsigned short* __restrict__ wq,
                                               unsigned short* __restrict__ wo) {
    int t = blockIdx.x * 256 + threadIdx.x;      // grid = 192*256 = 49152
    if (t < O3_ * C_) wq[t] = bf16_rne(Wqkv[t]);
    if (t < C_ * C_)  wo[t] = bf16_rne(Wout[t]);
}

// K1: per (b, 256-wide n-tile): 16 waves, 2 barriers/subtile, 2 blocks/CU (R11).
// Waves 0-11: gemm wave w owns qkv row-pair w (wq frags persistent in VGPRs).
// Waves 12-15: stage x subtiles, T14 issue-early/write-late, double-buffered xs.
// All 16 waves then run one context-MFMA tile each + S partial sums.
__global__ __launch_bounds__(1024) void k1_qkv(const float* __restrict__ x,
                                               const unsigned short* __restrict__ wq,
                                               unsigned short* __restrict__ qsm,
                                               float* __restrict__ ctx_part,
                                               float* __restrict__ S_part) {
    __shared__ __align__(16) unsigned short xs0[64 * 136];   // [n][c], stride 136 (dbuf A)
    __shared__ __align__(16) unsigned short xs1[64 * 136];   // dbuf B
    __shared__ __align__(16) unsigned short ek[128 * 72];    // [h*32+d][n], stride 72
    __shared__ __align__(16) unsigned short vsh[128 * 72];   // [h*32+e][n]

    const int b    = blockIdx.y;
    const int tblk = blockIdx.x;                 // 0..15
    const int tid  = threadIdx.x;

    const int lane = tid & 63;
    const int wv   = tid >> 6;                   // 0..15
    const int l15  = lane & 15;
    const int quad = lane >> 4;

    const float4v zero = {0.f, 0.f, 0.f, 0.f};

    // --- persistent wq fragments for gemm waves (loaded ONCE per block) ---
    short8 wfa[8];                               // [half(0: rows +0..15, 1: +16..31)*4 + kk]
    if (wv < 12) {
        const unsigned short* wqp = wq + (wv * 32 + l15) * C_ + quad * 8;
        #pragma unroll
        for (int kk = 0; kk < 4; kk++) {
            wfa[kk]     = *(const short8*)(wqp + kk * 32);
            wfa[4 + kk] = *(const short8*)(wqp + 16 * C_ + kk * 32);
        }
    }

    // --- staging lanes (waves 12-15): 256 threads, each 32 c-rows of one n ---
    const int sid = tid & 255;                   // for wv>=12: 0..255
    const int snl = sid & 63;                    // n within subtile
    const int scg = sid >> 6;                    // c group of 32
    const float* xbase = x + ((size_t)b * C_ + (size_t)scg * 32) * N_ + snl;
    float xv[32];                                // raw loads (issued one phase early)
    short8 c16[4];                               // converted subtile, write-late
    auto load_x = [&](int s) {
        const float* xp = xbase + (tblk * NSUB + s) * 64;
        #pragma unroll
        for (int i = 0; i < 32; i++) xv[i] = xp[(size_t)i * N_];
    };
    auto conv_x = [&]() {
        #pragma unroll
        for (int ii = 0; ii < 4; ii++) {
            short8 v8;
            #pragma unroll
            for (int j = 0; j < 8; j++) v8[j] = (short)bf16_rne(xv[ii * 8 + j]);
            c16[ii] = v8;
        }
    };
    auto store_c = [&](unsigned short* xs) {
        unsigned short* dst = &xs[snl * 136 + scg * 32];
        #pragma unroll
        for (int ii = 0; ii < 4; ii++) *(short8*)(dst + ii * 8) = c16[ii];
    };

    if (wv >= 12) {
        load_x(0); conv_x(); store_c(xs0);       // subtile 0 staged
        load_x(1);                               // subtile 1 loads in flight into phase 0
    }
    unsigned short* xs_cur = xs0;
    unsigned short* xs_nxt = xs1;

    float4v cacc = zero;                         // this wave's single ctx tile
    float s_acc  = 0.f;
    const int ch  = wv >> 2;                     // ctx tile coords (valid for all 16 wv)
    const int cdt = (wv >> 1) & 1;
    const int cet = wv & 1;

    for (int s = 0; s < NSUB; s++) {
        const int ns = (tblk * NSUB + s) * 64;
        __syncthreads();                         // A: xs_cur staged; ek/vsh free

        if (wv < 12) {
            #pragma unroll
            for (int ct = 0; ct < 4; ct++) {
                short8 bfx[4];
                #pragma unroll
                for (int kk = 0; kk < 4; kk++)
                    bfx[kk] = *(const short8*)&xs_cur[(ct * 16 + l15) * 136 + kk * 32 + quad * 8];
                float4v acc0 = zero, acc1 = zero;
                #pragma unroll
                for (int kk = 0; kk < 4; kk++) {
                    acc0 = __builtin_amdgcn_mfma_f32_16x16x32_bf16(wfa[kk],     bfx[kk], acc0, 0, 0, 0);
                    acc1 = __builtin_amdgcn_mfma_f32_16x16x32_bf16(wfa[4 + kk], bfx[kk], acc1, 0, 0, 0);
                }
                const int ncol = ct * 16 + l15;
                // C/D layout: col = l15, row = quad*4 + r (acc0: rows 0-15, acc1: 16-31)
                if (wv < 4) {                    // q, head h = wv: softmax over d per column
                    float e0[4], e1[4], z = 0.f;
                    #pragma unroll
                    for (int r = 0; r < 4; r++) {
                        e0[r] = __expf(acc0[r]); e1[r] = __expf(acc1[r]);
                        z += e0[r] + e1[r];
                    }
                    z += __shfl_xor(z, 16, 64);
                    z += __shfl_xor(z, 32, 64);
                    const float iz = 1.0f / z;
                    unsigned short* qp = qsm + ((size_t)b * N_ + ns + ncol) * C_ + wv * 32 + quad * 4;
                    short4v s0, s1;
                    #pragma unroll
                    for (int r = 0; r < 4; r++) {
                        s0[r] = (short)bf16_rne(e0[r] * iz);
                        s1[r] = (short)bf16_rne(e1[r] * iz);
                    }
                    *(short4v*)qp = s0;          // d = quad*4..+3
                    *(short4v*)(qp + 16) = s1;   // d = 16+quad*4..+3
                } else if (wv < 8) {             // k, head h = wv-4: exp -> LDS
                    const int row0 = (wv - 4) * 32 + quad * 4;
                    #pragma unroll
                    for (int r = 0; r < 4; r++) {
                        ek[(row0 + r) * 72 + ncol]      = bf16_rne(__expf(acc0[r]));
                        ek[(row0 + 16 + r) * 72 + ncol] = bf16_rne(__expf(acc1[r]));
                    }
                } else {                         // v, head h = wv-8 -> LDS
                    const int row0 = (wv - 8) * 32 + quad * 4;
                    #pragma unroll
                    for (int r = 0; r < 4; r++) {
                        vsh[(row0 + r) * 72 + ncol]      = bf16_rne(acc0[r]);
                        vsh[(row0 + 16 + r) * 72 + ncol] = bf16_rne(acc1[r]);
                    }
                }
            }
        } else {
            if (s + 1 < NSUB) { conv_x(); store_c(xs_nxt); }  // loads from phase s-1
            if (s + 2 < NSUB) load_x(s + 2);                  // issue only; consumed next phase
        }
        __syncthreads();                         // B: ek/vsh ready; xs_nxt staged

        // context: cacc[d][e] += sum_n expk[d][n] * v[e][n]  (one 16x16 tile per wave)
        {
            const unsigned short* ap = &ek[(ch * 32 + cdt * 16 + l15) * 72 + quad * 8];
            const unsigned short* bp = &vsh[(ch * 32 + cet * 16 + l15) * 72 + quad * 8];
            #pragma unroll
            for (int kk = 0; kk < 2; kk++) {
                short8 a  = *(const short8*)(ap + kk * 32);
                short8 bb = *(const short8*)(bp + kk * 32);
                cacc = __builtin_amdgcn_mfma_f32_16x16x32_bf16(a, bb, cacc, 0, 0, 0);
            }
        }
        {   // S partial sums: 1024 threads = 128 rows x 8 threads x 8 elems
            const unsigned short* ep = &ek[(tid >> 3) * 72 + (tid & 7) * 8];
            short8 e0 = *(const short8*)ep;      // one ds_read_b128
            float ss = 0.f;
            #pragma unroll
            for (int j = 0; j < 8; j++) ss += bf2f((unsigned short)e0[j]);
            s_acc += ss;
        }
        { unsigned short* t = xs_cur; xs_cur = xs_nxt; xs_nxt = t; }
    }

    // write-out: plain stores, no atomics
    {
        float* cp = ctx_part + ((size_t)(b * TPB_ + tblk) << 12)
                  + ((ch * 32 + cdt * 16 + quad * 4) * 32 + cet * 16 + l15);
        #pragma unroll
        for (int r = 0; r < 4; r++) cp[r * 32] = cacc[r];
    }
    {
        float ss = s_acc;
        ss += __shfl_xor(ss, 1, 64);
        ss += __shfl_xor(ss, 2, 64);
        ss += __shfl_xor(ss, 4, 64);
        if ((tid & 7) == 0)
            S_part[(size_t)(b * TPB_ + tblk) * 128 + (tid >> 3)] = ss;
    }
}

// K2a: reduce 16 ctx partials + fold 1/S -> ctxn bf16 [b][hd][e] (flat [b][4096]).
// Grid 256 blocks (8/batch) x 256 thr: each thread 2 elems x 16 partials, full ILP.
__global__ __launch_bounds__(256) void k2a_reduce(const float* __restrict__ ctx_part,
                                                  const float* __restrict__ S_part,
                                                  unsigned short* __restrict__ ctxn) {
    __shared__ float Sinv[16];
    const int b     = blockIdx.x >> 3;
    const int chunk = blockIdx.x & 7;            // 512 elems (16 hd rows) per block
    const int tid   = threadIdx.x;
    if (tid < 16) {
        const int hd = chunk * 16 + tid;
        float s = 0.f;
        #pragma unroll
        for (int t = 0; t < TPB_; t++)
            s += S_part[(size_t)(b * TPB_ + t) * 128 + hd];
        Sinv[tid] = 1.0f / s;
    }
    __syncthreads();
    #pragma unroll
    for (int j = 0; j < 2; j++) {
        const int ei = chunk * 512 + j * 256 + tid;   // flat [hd][e]
        float v = 0.f;
        #pragma unroll
        for (int t = 0; t < TPB_; t++)
            v += ctx_part[((size_t)(b * TPB_ + t) << 12) + ei];
        ctxn[(size_t)b * 4096 + ei] = bf16_rne(v * Sinv[(ei >> 5) - chunk * 16]);
    }
}

// K2b: Wbig[b][o][hd] = sum_e wo[o][h*32+e] * ctxN[b][hd][e], written in FRAG-MAJOR
// tiled order: chunk c = (o>>4)*4 + (hd>>5); within chunk, lane' = ((hd>>3)&3)*16 + (o&15),
// short j = hd&7. k3 then stages linearly and reads lane-contiguous ds_read_b128.
// Grid 32 blocks x 512 thr; wave wv owns o-tile wv. All 12 loads hoisted (ILP).
// NOTE: wbig aliases ctx_part's space -- legal because k2a (last reader of ctx_part)
// completes before k2b launches on the same stream.
__global__ __launch_bounds__(512) void k2b_fold(const unsigned short* __restrict__ ctxn,
                                                const unsigned short* __restrict__ wo,
                                                unsigned short* __restrict__ wbig) {
    const int b   = blockIdx.x;
    const int tid = threadIdx.x;
    const int lane = tid & 63, wv = tid >> 6, l15 = lane & 15, quad = lane >> 4;
    const float4v zero = {0.f, 0.f, 0.f, 0.f};

    short8 a4[4], b8[8];
    #pragma unroll
    for (int h = 0; h < 4; h++)
        a4[h] = *(const short8*)(wo + (wv * 16 + l15) * C_ + h * 32 + quad * 8);
    #pragma unroll
    for (int ht = 0; ht < 8; ht++)
        b8[ht] = *(const short8*)(ctxn + (size_t)b * 4096
                                  + ((ht >> 1) * 32 + (ht & 1) * 16 + l15) * 32 + quad * 8);

    unsigned short* wb = wbig + (size_t)b * (C_ * C_);
    #pragma unroll
    for (int ht = 0; ht < 8; ht++) {
        float4v c4 = __builtin_amdgcn_mfma_f32_16x16x32_bf16(a4[ht >> 1], b8[ht], zero, 0, 0, 0);
        // value (r): o = wv*16+quad*4+r, hd = ht*16+l15
        const int c     = wv * 4 + (ht >> 1);
        const int quadp = (ht & 1) * 2 + (l15 >> 3);
        #pragma unroll
        for (int r = 0; r < 4; r++)
            wb[((c * 64 + quadp * 16 + quad * 4 + r) << 3) + (l15 & 7)] = bf16_rne(c4[r]);
    }
}

// K3: grid-stride persistent y = Wbig[b] @ qsm + bout, LayerNorm over c.
// 512 blocks (2/CU) x 512 thr; each block owns 256 n-cols = 2 tiles of 128.
// wbig (32KB frag-major) + bout/lnw/lnb staged into LDS ONCE per block; per tile the
// next tile's qsm frags are prefetched before the MFMA+store phase. One barrier total.
__global__ __launch_bounds__(512) void k3_out(const unsigned short* __restrict__ qsm,
                                              const unsigned short* __restrict__ wbig,
                                              const float* __restrict__ bout,
                                              const float* __restrict__ lnw,
                                              const float* __restrict__ lnb,
                                              float* __restrict__ out) {
    __shared__ __align__(16) unsigned short wls[16384];      // 32KB
    __shared__ float lnp[384];                               // bout | lnw | lnb

    const int b    = blockIdx.y;
    const int tseg = blockIdx.x;                 // 0..15: n-cols tseg*256 .. +255
    const int tid  = threadIdx.x;

    const int lane = tid & 63, wv = tid >> 6, l15 = lane & 15, quad = lane >> 4;
    const int nl = wv * 16 + l15;                // 0..127 within tile

    const float4v zero = {0.f, 0.f, 0.f, 0.f};
    const size_t n0base = (size_t)tseg * 256;

    // stage Wbig[b] 32KB -> LDS (linear: thread t copies 16B chunks t, t+512, ...)
    short8 st[4];
    {
        const short8* src = (const short8*)(wbig + (size_t)b * (C_ * C_));
        #pragma unroll
        for (int i = 0; i < 4; i++) st[i] = src[i * 512 + tid];
    }
    if (tid < 128) {
        lnp[tid]       = bout[tid];
        lnp[128 + tid] = lnw[tid];
        lnp[256 + tid] = lnb[tid];
    }
    // first tile's qsm B-frags (independent; overlap the stage)
    short8 bq[4], bqn[4];
    {
        const unsigned short* qp = qsm + ((size_t)b * N_ + n0base + nl) * C_ + quad * 8;
        #pragma unroll
        for (int kk = 0; kk < 4; kk++) bq[kk] = *(const short8*)(qp + kk * 32);
    }
    #pragma unroll
    for (int i = 0; i < 4; i++)
        *(short8*)&wls[(i * 512 + tid) * 8] = st[i];
    __syncthreads();

    #pragma unroll
    for (int t = 0; t < 2; t++) {
        const size_t n = n0base + t * 128 + nl;
        if (t == 0) {                            // prefetch next tile's frags
            const unsigned short* qp = qsm + ((size_t)b * N_ + n0base + 128 + nl) * C_ + quad * 8;
            #pragma unroll
            for (int kk = 0; kk < 4; kk++) bqn[kk] = *(const short8*)(qp + kk * 32);
        }

        float4v acc[8];
        #pragma unroll
        for (int ot = 0; ot < 8; ot++) {
            float4v a = zero;
            #pragma unroll
            for (int kk = 0; kk < 4; kk++) {
                short8 w = *(const short8*)&wls[((ot * 4 + kk) * 64 + lane) * 8];
                a = __builtin_amdgcn_mfma_f32_16x16x32_bf16(w, bq[kk], a, 0, 0, 0);
            }
            acc[ot] = a;
        }

        // bias + LayerNorm over the 128 channels of this column
        float sum = 0.f, sq = 0.f;
        #pragma unroll
        for (int ot = 0; ot < 8; ot++) {
            #pragma unroll
            for (int r = 0; r < 4; r++) {
                const int o = ot * 16 + quad * 4 + r;
                const float y = acc[ot][r] + lnp[o];
                acc[ot][r] = y;
                sum += y; sq += y * y;
            }
        }
        sum += __shfl_xor(sum, 16, 64);
        sum += __shfl_xor(sum, 32, 64);
        sq  += __shfl_xor(sq, 16, 64);
        sq  += __shfl_xor(sq, 32, 64);
        const float mean = sum * (1.0f / 128.0f);
        const float var  = sq * (1.0f / 128.0f) - mean * mean;   // biased, matches jnp.var
        const float rstd = rsqrtf(var + 1e-5f);

        #pragma unroll
        for (int ot = 0; ot < 8; ot++) {
            #pragma unroll
            for (int r = 0; r < 4; r++) {
                const int o = ot * 16 + quad * 4 + r;
                out[((size_t)b * C_ + o) * N_ + n] = (acc[ot][r] - mean) * rstd * lnp[128 + o] + lnp[256 + o];
            }
        }

        #pragma unroll
        for (int kk = 0; kk < 4; kk++) bq[kk] = bqn[kk];
    }
}

extern "C" void kernel_launch(void* const* d_in, const int* in_sizes, int n_in,
                              void* d_out, int out_size, void* d_ws, size_t ws_size,
                              hipStream_t stream) {
    const float* x    = (const float*)d_in[0];
    const float* Wqkv = (const float*)d_in[1];
    const float* Wout = (const float*)d_in[2];
    const float* bout = (const float*)d_in[3];
    const float* lnw  = (const float*)d_in[4];
    const float* lnb  = (const float*)d_in[5];
    float* out = (float*)d_out;

    char* ws = (char*)d_ws;
    unsigned short* wq   = (unsigned short*)(ws + OFF_WQ);
    unsigned short* wo   = (unsigned short*)(ws + OFF_WO);
    float* S_part        = (float*)(ws + OFF_SP);
    float* ctx_part      = (float*)(ws + OFF_CTXP);
    unsigned short* ctxn = (unsigned short*)(ws + OFF_CTXN);
    unsigned short* wbig = (unsigned short*)(ws + OFF_WBIG);   // aliases ctx_part (dead)
    unsigned short* qsm  = (unsigned short*)(ws + OFF_QSM);

    k0_prep<<<192, 256, 0, stream>>>(Wqkv, Wout, wq, wo);
    k1_qkv<<<dim3(TPB_, B_), 1024, 0, stream>>>(x, wq, qsm, ctx_part, S_part);
    k2a_reduce<<<B_ * 8, 256, 0, stream>>>(ctx_part, S_part, ctxn);
    k2b_fold<<<B_, 512, 0, stream>>>(ctxn, wo, wbig);
    k3_out<<<dim3(16, B_), 512, 0, stream>>>(qsm, wbig, bout, lnw, lnb, out);
}

// Round 7
// 158.896 us; speedup vs baseline: 1.0360x; 1.0360x over previous
//
#include <hip/hip_runtime.h>
#include <stdint.h>

// LinearAttention fused: qkv GEMM + dual softmax + linear attention + Wout GEMM + LayerNorm2d
// Shapes: b=32, c=128, n=64*64=4096, heads=4, dim_head=32.
// All GEMMs via v_mfma_f32_16x16x32_bf16 (fp32 accum).
//
// R5: k1 rebuilt: 1024-thr blocks, 16 waves, wq frags persistent in VGPRs. 181us.
// R6: algebraic fold y = (Wout @ blockdiag_h(ctxN)) @ qsm = Wbig[b] @ qsm.
// R7: Wbig frag-major + k3 LDS-staged inner loop; k2 split. 159.9us (-17.8).
// R8/R9: k3 TLP + persistent: ~neutral (158.4). R10: k1 barrier merge REGRESSED
//      (161.4, k1=43.1us). R11: k1 TPB 16 / 2 blocks/CU REGRESSED (164.6, k1=43.6us).
//      KEY EVIDENCE: k1 invariant 43us at 1 vs 2 blocks/CU => NOT residency-bound.
//      Census: MFMA 5us, VALU 12us, HBM 12us, LDS-pipe ~17us (192 b128 B-reads,
//      2048 ds_write_u16, S-sum pass), 2.2M bank-conflict cycles mostly on the
//      S-sum read (bank = 4*(r+c)%32, ~8-way).
// R12: REVERT to R9 (TPB=8, NSUB=8, 2-barrier, T14 staging) + remove the S-sum LDS
//      pass: k-waves accumulate S from their f32 exp values in registers (8 adds/ct),
//      one shfl_xor(1,2,4,8) reduce at kernel end. Removes per-subtile conflicted
//      ds_read_b128 + 8 cvt/adds for all 16 waves. S now summed pre-rounding
//      (closer to f32 reference).

constexpr int B_   = 32;
constexpr int C_   = 128;
constexpr int N_   = 4096;
constexpr int O3_  = 384;   // 3*128 qkv rows
constexpr int NSUB = 8;     // 64-wide n-subtiles per k1 block
constexpr int TPB_ = 8;     // k1 blocks per batch (4096 / 512)

using short8  = __attribute__((ext_vector_type(8))) short;
using short4v = __attribute__((ext_vector_type(4))) short;
using float4v = __attribute__((ext_vector_type(4))) float;

__device__ __forceinline__ unsigned short bf16_rne(float f) {
    union { float f; uint32_t u; } v; v.f = f;
    uint32_t u = v.u;
    u += 0x7FFFu + ((u >> 16) & 1u);   // round-to-nearest-even
    return (unsigned short)(u >> 16);
}
__device__ __forceinline__ float bf2f(unsigned short h) {
    union { uint32_t u; float f; } v; v.u = ((uint32_t)h) << 16; return v.f;
}

// workspace layout (bytes)
constexpr size_t OFF_WQ   = 0;          // Wqkv bf16: 384*128*2 = 98304
constexpr size_t OFF_WO   = 98304;      // Wout bf16: 32768 -> 131072
constexpr size_t OFF_SP   = 131072;     // S partials [b][8][128] f32: 131072 -> 262144
constexpr size_t OFF_CTXP = 262144;     // ctx partials [b][8][4096] f32: 4194304 -> 4456448
constexpr size_t OFF_CTXN = 4456448;    // ctxN bf16 [b][hd][e]: 262144 -> 4718592
constexpr size_t OFF_WBIG = 4718592;    // Wbig bf16 TILED: 1048576 -> 5767168
constexpr size_t OFF_QSM  = 5767168;    // q-softmax bf16 [b][n][h*32+d]: 33554432 -> 39321600
// total 39,321,600 bytes

__global__ __launch_bounds__(256) void k0_prep(const float* __restrict__ Wqkv,
                                               const float* __restrict__ Wout,
                                               unsigned short* __restrict__ wq,
                                               unsigned short* __restrict__ wo) {
    int t = blockIdx.x * 256 + threadIdx.x;      // grid = 192*256 = 49152
    if (t < O3_ * C_) wq[t] = bf16_rne(Wqkv[t]);
    if (t < C_ * C_)  wo[t] = bf16_rne(Wout[t]);
}

// K1: per (b, 512-wide n-tile): 16 waves. Waves 0-11: gemm wave w owns qkv row-pair w
// (rows w*32..w*32+31) with wq frags persistent in registers; covers all 64 n-cols.
// Waves 12-15: stage x subtiles, T14 issue-early/write-late, double-buffered xs.
// R12: S accumulated in k-wave registers (no per-subtile LDS S pass).
__global__ __launch_bounds__(1024) void k1_qkv(const float* __restrict__ x,
                                               const unsigned short* __restrict__ wq,
                                               unsigned short* __restrict__ qsm,
                                               float* __restrict__ ctx_part,
                                               float* __restrict__ S_part) {
    __shared__ __align__(16) unsigned short xs0[64 * 136];   // [n][c], stride 136 (dbuf A)
    __shared__ __align__(16) unsigned short xs1[64 * 136];   // dbuf B
    __shared__ __align__(16) unsigned short ek[128 * 72];    // [h*32+d][n], stride 72
    __shared__ __align__(16) unsigned short vsh[128 * 72];   // [h*32+e][n]

    const int b    = blockIdx.y;
    const int tblk = blockIdx.x;                 // 0..7
    const int tid  = threadIdx.x;

    const int lane = tid & 63;
    const int wv   = tid >> 6;                   // 0..15
    const int l15  = lane & 15;
    const int quad = lane >> 4;

    const float4v zero = {0.f, 0.f, 0.f, 0.f};

    // --- persistent wq fragments for gemm waves (loaded ONCE per block) ---
    short8 wfa[8];                               // [half(0: rows +0..15, 1: +16..31)*4 + kk]
    if (wv < 12) {
        const unsigned short* wqp = wq + (wv * 32 + l15) * C_ + quad * 8;
        #pragma unroll
        for (int kk = 0; kk < 4; kk++) {
            wfa[kk]     = *(const short8*)(wqp + kk * 32);
            wfa[4 + kk] = *(const short8*)(wqp + 16 * C_ + kk * 32);
        }
    }

    // --- staging lanes (waves 12-15): 256 threads, each 32 c-rows of one n ---
    const int sid = tid & 255;                   // for wv>=12: 0..255
    const int snl = sid & 63;                    // n within subtile
    const int scg = sid >> 6;                    // c group of 32
    const float* xbase = x + ((size_t)b * C_ + (size_t)scg * 32) * N_ + snl;
    float xv[32];                                // raw loads (issued one phase early)
    short8 c16[4];                               // converted subtile, write-late
    auto load_x = [&](int s) {
        const float* xp = xbase + (tblk * NSUB + s) * 64;
        #pragma unroll
        for (int i = 0; i < 32; i++) xv[i] = xp[(size_t)i * N_];
    };
    auto conv_x = [&]() {
        #pragma unroll
        for (int ii = 0; ii < 4; ii++) {
            short8 v8;
            #pragma unroll
            for (int j = 0; j < 8; j++) v8[j] = (short)bf16_rne(xv[ii * 8 + j]);
            c16[ii] = v8;
        }
    };
    auto store_c = [&](unsigned short* xs) {
        unsigned short* dst = &xs[snl * 136 + scg * 32];
        #pragma unroll
        for (int ii = 0; ii < 4; ii++) *(short8*)(dst + ii * 8) = c16[ii];
    };

    if (wv >= 12) {
        load_x(0); conv_x(); store_c(xs0);       // subtile 0 staged
        load_x(1);                               // subtile 1 loads in flight into phase 0
    }
    unsigned short* xs_cur = xs0;
    unsigned short* xs_nxt = xs1;

    float4v cacc = zero;                         // this wave's single ctx tile
    float sk0[4] = {0.f, 0.f, 0.f, 0.f};         // S partial accum (k waves only)
    float sk1[4] = {0.f, 0.f, 0.f, 0.f};
    const int ch  = wv >> 2;                     // ctx tile coords (valid for all 16 wv)
    const int cdt = (wv >> 1) & 1;
    const int cet = wv & 1;

    for (int s = 0; s < NSUB; s++) {
        const int ns = (tblk * NSUB + s) * 64;
        __syncthreads();                         // A: xs_cur staged; ek/vsh free

        if (wv < 12) {
            #pragma unroll
            for (int ct = 0; ct < 4; ct++) {
                short8 bfx[4];
                #pragma unroll
                for (int kk = 0; kk < 4; kk++)
                    bfx[kk] = *(const short8*)&xs_cur[(ct * 16 + l15) * 136 + kk * 32 + quad * 8];
                float4v acc0 = zero, acc1 = zero;
                #pragma unroll
                for (int kk = 0; kk < 4; kk++) {
                    acc0 = __builtin_amdgcn_mfma_f32_16x16x32_bf16(wfa[kk],     bfx[kk], acc0, 0, 0, 0);
                    acc1 = __builtin_amdgcn_mfma_f32_16x16x32_bf16(wfa[4 + kk], bfx[kk], acc1, 0, 0, 0);
                }
                const int ncol = ct * 16 + l15;
                // C/D layout: col = l15, row = quad*4 + r (acc0: rows 0-15, acc1: 16-31)
                if (wv < 4) {                    // q, head h = wv: softmax over d per column
                    float e0[4], e1[4], z = 0.f;
                    #pragma unroll
                    for (int r = 0; r < 4; r++) {
                        e0[r] = __expf(acc0[r]); e1[r] = __expf(acc1[r]);
                        z += e0[r] + e1[r];
                    }
                    z += __shfl_xor(z, 16, 64);
                    z += __shfl_xor(z, 32, 64);
                    const float iz = 1.0f / z;
                    unsigned short* qp = qsm + ((size_t)b * N_ + ns + ncol) * C_ + wv * 32 + quad * 4;
                    short4v s0, s1;
                    #pragma unroll
                    for (int r = 0; r < 4; r++) {
                        s0[r] = (short)bf16_rne(e0[r] * iz);
                        s1[r] = (short)bf16_rne(e1[r] * iz);
                    }
                    *(short4v*)qp = s0;          // d = quad*4..+3
                    *(short4v*)(qp + 16) = s1;   // d = 16+quad*4..+3
                } else if (wv < 8) {             // k, head h = wv-4: exp -> LDS + S accum
                    const int row0 = (wv - 4) * 32 + quad * 4;
                    #pragma unroll
                    for (int r = 0; r < 4; r++) {
                        const float e0v = __expf(acc0[r]);
                        const float e1v = __expf(acc1[r]);
                        ek[(row0 + r) * 72 + ncol]      = bf16_rne(e0v);
                        ek[(row0 + 16 + r) * 72 + ncol] = bf16_rne(e1v);
                        sk0[r] += e0v;
                        sk1[r] += e1v;
                    }
                } else {                         // v, head h = wv-8 -> LDS
                    const int row0 = (wv - 8) * 32 + quad * 4;
                    #pragma unroll
                    for (int r = 0; r < 4; r++) {
                        vsh[(row0 + r) * 72 + ncol]      = bf16_rne(acc0[r]);
                        vsh[(row0 + 16 + r) * 72 + ncol] = bf16_rne(acc1[r]);
                    }
                }
            }
        } else {
            if (s + 1 < NSUB) { conv_x(); store_c(xs_nxt); }  // loads from phase s-1
            if (s + 2 < NSUB) load_x(s + 2);                  // issue only; consumed next phase
        }
        __syncthreads();                         // B: ek/vsh ready; xs_nxt staged

        // context: cacc[d][e] += sum_n expk[d][n] * v[e][n]  (one 16x16 tile per wave)
        {
            const unsigned short* ap = &ek[(ch * 32 + cdt * 16 + l15) * 72 + quad * 8];
            const unsigned short* bp = &vsh[(ch * 32 + cet * 16 + l15) * 72 + quad * 8];
            #pragma unroll
            for (int kk = 0; kk < 2; kk++) {
                short8 a  = *(const short8*)(ap + kk * 32);
                short8 bb = *(const short8*)(bp + kk * 32);
                cacc = __builtin_amdgcn_mfma_f32_16x16x32_bf16(a, bb, cacc, 0, 0, 0);
            }
        }
        { unsigned short* t = xs_cur; xs_cur = xs_nxt; xs_nxt = t; }
    }

    // write-out: plain stores, no atomics
    {
        float* cp = ctx_part + ((size_t)(b * TPB_ + tblk) << 12)
                  + ((ch * 32 + cdt * 16 + quad * 4) * 32 + cet * 16 + l15);
        #pragma unroll
        for (int r = 0; r < 4; r++) cp[r * 32] = cacc[r];
    }
    // S: k-waves reduce their register partials over the 16-lane column group
    if (wv >= 4 && wv < 8) {
        const int srow = (wv - 4) * 32 + quad * 4;
        float* sp = S_part + (size_t)(b * TPB_ + tblk) * 128;
        #pragma unroll
        for (int r = 0; r < 4; r++) {
            float a0 = sk0[r], a1 = sk1[r];
            a0 += __shfl_xor(a0, 1, 64); a0 += __shfl_xor(a0, 2, 64);
            a0 += __shfl_xor(a0, 4, 64); a0 += __shfl_xor(a0, 8, 64);
            a1 += __shfl_xor(a1, 1, 64); a1 += __shfl_xor(a1, 2, 64);
            a1 += __shfl_xor(a1, 4, 64); a1 += __shfl_xor(a1, 8, 64);
            if (l15 == 0) { sp[srow + r] = a0; sp[srow + 16 + r] = a1; }
        }
    }
}

// K2a: reduce 8 ctx partials + fold 1/S -> ctxn bf16 [b][hd][e] (flat [b][4096]).
// Grid 256 blocks (8/batch) x 256 thr: each thread 2 elems x 8 partials, full ILP.
__global__ __launch_bounds__(256) void k2a_reduce(const float* __restrict__ ctx_part,
                                                  const float* __restrict__ S_part,
                                                  unsigned short* __restrict__ ctxn) {
    __shared__ float Sinv[16];
    const int b     = blockIdx.x >> 3;
    const int chunk = blockIdx.x & 7;            // 512 elems (16 hd rows) per block
    const int tid   = threadIdx.x;
    if (tid < 16) {
        const int hd = chunk * 16 + tid;
        float s = 0.f;
        #pragma unroll
        for (int t = 0; t < TPB_; t++)
            s += S_part[(size_t)(b * TPB_ + t) * 128 + hd];
        Sinv[tid] = 1.0f / s;
    }
    __syncthreads();
    #pragma unroll
    for (int j = 0; j < 2; j++) {
        const int ei = chunk * 512 + j * 256 + tid;   // flat [hd][e]
        float v = 0.f;
        #pragma unroll
        for (int t = 0; t < TPB_; t++)
            v += ctx_part[((size_t)(b * TPB_ + t) << 12) + ei];
        ctxn[(size_t)b * 4096 + ei] = bf16_rne(v * Sinv[(ei >> 5) - chunk * 16]);
    }
}

// K2b: Wbig[b][o][hd] = sum_e wo[o][h*32+e] * ctxN[b][hd][e], written in FRAG-MAJOR
// tiled order: chunk c = (o>>4)*4 + (hd>>5); within chunk, lane' = ((hd>>3)&3)*16 + (o&15),
// short j = hd&7. k3 then stages linearly and reads lane-contiguous ds_read_b128.
// Grid 32 blocks x 512 thr; wave wv owns o-tile wv. All 12 loads hoisted (ILP).
__global__ __launch_bounds__(512) void k2b_fold(const unsigned short* __restrict__ ctxn,
                                                const unsigned short* __restrict__ wo,
                                                unsigned short* __restrict__ wbig) {
    const int b   = blockIdx.x;
    const int tid = threadIdx.x;
    const int lane = tid & 63, wv = tid >> 6, l15 = lane & 15, quad = lane >> 4;
    const float4v zero = {0.f, 0.f, 0.f, 0.f};

    short8 a4[4], b8[8];
    #pragma unroll
    for (int h = 0; h < 4; h++)
        a4[h] = *(const short8*)(wo + (wv * 16 + l15) * C_ + h * 32 + quad * 8);
    #pragma unroll
    for (int ht = 0; ht < 8; ht++)
        b8[ht] = *(const short8*)(ctxn + (size_t)b * 4096
                                  + ((ht >> 1) * 32 + (ht & 1) * 16 + l15) * 32 + quad * 8);

    unsigned short* wb = wbig + (size_t)b * (C_ * C_);
    #pragma unroll
    for (int ht = 0; ht < 8; ht++) {
        float4v c4 = __builtin_amdgcn_mfma_f32_16x16x32_bf16(a4[ht >> 1], b8[ht], zero, 0, 0, 0);
        // value (r): o = wv*16+quad*4+r, hd = ht*16+l15
        const int c     = wv * 4 + (ht >> 1);
        const int quadp = (ht & 1) * 2 + (l15 >> 3);
        #pragma unroll
        for (int r = 0; r < 4; r++)
            wb[((c * 64 + quadp * 16 + quad * 4 + r) << 3) + (l15 & 7)] = bf16_rne(c4[r]);
    }
}

// K3: grid-stride persistent y = Wbig[b] @ qsm + bout, LayerNorm over c.
// 512 blocks (2/CU) x 512 thr; each block owns 256 n-cols = 2 tiles of 128.
// wbig (32KB frag-major) + bout/lnw/lnb staged into LDS ONCE per block; per tile the
// next tile's qsm frags are prefetched before the MFMA+store phase. One barrier total.
__global__ __launch_bounds__(512) void k3_out(const unsigned short* __restrict__ qsm,
                                              const unsigned short* __restrict__ wbig,
                                              const float* __restrict__ bout,
                                              const float* __restrict__ lnw,
                                              const float* __restrict__ lnb,
                                              float* __restrict__ out) {
    __shared__ __align__(16) unsigned short wls[16384];      // 32KB
    __shared__ float lnp[384];                               // bout | lnw | lnb

    const int b    = blockIdx.y;
    const int tseg = blockIdx.x;                 // 0..15: n-cols tseg*256 .. +255
    const int tid  = threadIdx.x;

    const int lane = tid & 63, wv = tid >> 6, l15 = lane & 15, quad = lane >> 4;
    const int nl = wv * 16 + l15;                // 0..127 within tile

    const float4v zero = {0.f, 0.f, 0.f, 0.f};
    const size_t n0base = (size_t)tseg * 256;

    // stage Wbig[b] 32KB -> LDS (linear: thread t copies 16B chunks t, t+512, ...)
    short8 st[4];
    {
        const short8* src = (const short8*)(wbig + (size_t)b * (C_ * C_));
        #pragma unroll
        for (int i = 0; i < 4; i++) st[i] = src[i * 512 + tid];
    }
    if (tid < 128) {
        lnp[tid]       = bout[tid];
        lnp[128 + tid] = lnw[tid];
        lnp[256 + tid] = lnb[tid];
    }
    // first tile's qsm B-frags (independent; overlap the stage)
    short8 bq[4], bqn[4];
    {
        const unsigned short* qp = qsm + ((size_t)b * N_ + n0base + nl) * C_ + quad * 8;
        #pragma unroll
        for (int kk = 0; kk < 4; kk++) bq[kk] = *(const short8*)(qp + kk * 32);
    }
    #pragma unroll
    for (int i = 0; i < 4; i++)
        *(short8*)&wls[(i * 512 + tid) * 8] = st[i];
    __syncthreads();

    #pragma unroll
    for (int t = 0; t < 2; t++) {
        const size_t n = n0base + t * 128 + nl;
        if (t == 0) {                            // prefetch next tile's frags
            const unsigned short* qp = qsm + ((size_t)b * N_ + n0base + 128 + nl) * C_ + quad * 8;
            #pragma unroll
            for (int kk = 0; kk < 4; kk++) bqn[kk] = *(const short8*)(qp + kk * 32);
        }

        float4v acc[8];
        #pragma unroll
        for (int ot = 0; ot < 8; ot++) {
            float4v a = zero;
            #pragma unroll
            for (int kk = 0; kk < 4; kk++) {
                short8 w = *(const short8*)&wls[((ot * 4 + kk) * 64 + lane) * 8];
                a = __builtin_amdgcn_mfma_f32_16x16x32_bf16(w, bq[kk], a, 0, 0, 0);
            }
            acc[ot] = a;
        }

        // bias + LayerNorm over the 128 channels of this column
        float sum = 0.f, sq = 0.f;
        #pragma unroll
        for (int ot = 0; ot < 8; ot++) {
            #pragma unroll
            for (int r = 0; r < 4; r++) {
                const int o = ot * 16 + quad * 4 + r;
                const float y = acc[ot][r] + lnp[o];
                acc[ot][r] = y;
                sum += y; sq += y * y;
            }
        }
        sum += __shfl_xor(sum, 16, 64);
        sum += __shfl_xor(sum, 32, 64);
        sq  += __shfl_xor(sq, 16, 64);
        sq  += __shfl_xor(sq, 32, 64);
        const float mean = sum * (1.0f / 128.0f);
        const float var  = sq * (1.0f / 128.0f) - mean * mean;   // biased, matches jnp.var
        const float rstd = rsqrtf(var + 1e-5f);

        #pragma unroll
        for (int ot = 0; ot < 8; ot++) {
            #pragma unroll
            for (int r = 0; r < 4; r++) {
                const int o = ot * 16 + quad * 4 + r;
                out[((size_t)b * C_ + o) * N_ + n] = (acc[ot][r] - mean) * rstd * lnp[128 + o] + lnp[256 + o];
            }
        }

        #pragma unroll
        for (int kk = 0; kk < 4; kk++) bq[kk] = bqn[kk];
    }
}

extern "C" void kernel_launch(void* const* d_in, const int* in_sizes, int n_in,
                              void* d_out, int out_size, void* d_ws, size_t ws_size,
                              hipStream_t stream) {
    const float* x    = (const float*)d_in[0];
    const float* Wqkv = (const float*)d_in[1];
    const float* Wout = (const float*)d_in[2];
    const float* bout = (const float*)d_in[3];
    const float* lnw  = (const float*)d_in[4];
    const float* lnb  = (const float*)d_in[5];
    float* out = (float*)d_out;

    char* ws = (char*)d_ws;
    unsigned short* wq   = (unsigned short*)(ws + OFF_WQ);
    unsigned short* wo   = (unsigned short*)(ws + OFF_WO);
    float* S_part        = (float*)(ws + OFF_SP);
    float* ctx_part      = (float*)(ws + OFF_CTXP);
    unsigned short* ctxn = (unsigned short*)(ws + OFF_CTXN);
    unsigned short* wbig = (unsigned short*)(ws + OFF_WBIG);
    unsigned short* qsm  = (unsigned short*)(ws + OFF_QSM);

    k0_prep<<<192, 256, 0, stream>>>(Wqkv, Wout, wq, wo);
    k1_qkv<<<dim3(TPB_, B_), 1024, 0, stream>>>(x, wq, qsm, ctx_part, S_part);
    k2a_reduce<<<B_ * 8, 256, 0, stream>>>(ctx_part, S_part, ctxn);
    k2b_fold<<<B_, 512, 0, stream>>>(ctxn, wo, wbig);
    k3_out<<<dim3(16, B_), 512, 0, stream>>>(qsm, wbig, bout, lnw, lnb, out);
}

// Round 9
// 157.508 us; speedup vs baseline: 1.0451x; 1.0088x over previous
//
#include <hip/hip_runtime.h>
#include <stdint.h>

// LinearAttention fused: qkv GEMM + dual softmax + linear attention + Wout GEMM + LayerNorm2d
// Shapes: b=32, c=128, n=64*64=4096, heads=4, dim_head=32.
// All GEMMs via v_mfma_f32_16x16x32_bf16 (fp32 accum).
//
// R5: k1 rebuilt: 1024-thr blocks, 16 waves, wq frags persistent in VGPRs. 181us.
// R6: algebraic fold y = (Wout @ blockdiag_h(ctxN)) @ qsm = Wbig[b] @ qsm.
// R7: Wbig frag-major + k3 LDS-staged inner loop; k2 split. 159.9us (-17.8).
// R8-R12: five k1/k3 schedule variants all neutral/regressed; k1 invariant ~43us
//      across 1 vs 2 blocks/CU, 9 vs 16 barriers; no pipe >45%.
// R13: v_cvt_pk_bf16_f32 FAILED correctness (absmax 0.506): its rounding is NOT
//      RNE-equivalent to bf16_rne. Reverted — do not use cvt_pk where bit-exact
//      RNE matters.
// R14: zero-numerics-risk consolidation: (a) k0 deleted — k1 converts Wqkv frags
//      f32->bf16 in registers at block start (same bf16_rne, amortized over 8
//      subtiles); (b) k2a+k2b fused into one 32-block kernel with ctxn in LDS
//      (R6's padded [128][40] layout) — ctxn global round trip gone. 5 launches -> 3.
//      k1/k3 otherwise byte-identical to R12.

constexpr int B_   = 32;
constexpr int C_   = 128;
constexpr int N_   = 4096;
constexpr int NSUB = 8;     // 64-wide n-subtiles per k1 block
constexpr int TPB_ = 8;     // k1 blocks per batch (4096 / 512)

using short8  = __attribute__((ext_vector_type(8))) short;
using short4v = __attribute__((ext_vector_type(4))) short;
using float4v = __attribute__((ext_vector_type(4))) float;

__device__ __forceinline__ unsigned short bf16_rne(float f) {
    union { float f; uint32_t u; } v; v.f = f;
    uint32_t u = v.u;
    u += 0x7FFFu + ((u >> 16) & 1u);   // round-to-nearest-even
    return (unsigned short)(u >> 16);
}

// workspace layout (bytes)
constexpr size_t OFF_SP   = 0;          // S partials [b][8][128] f32: 131072
constexpr size_t OFF_CTXP = 131072;     // ctx partials [b][8][4096] f32: 4194304 -> 4325376
constexpr size_t OFF_WBIG = 4325376;    // Wbig bf16 TILED: 1048576 -> 5373952
constexpr size_t OFF_QSM  = 5373952;    // q-softmax bf16 [b][n][h*32+d]: 33554432 -> 38928384
// total 38,928,384 bytes

// K1: per (b, 512-wide n-tile): 16 waves. Waves 0-11: gemm wave w owns qkv row-pair w
// (rows w*32..w*32+31); wq fragments converted from f32 Wqkv ONCE per block into
// persistent registers. Waves 12-15: stage x subtiles (T14 issue-early/write-late,
// double-buffered xs). S accumulated in k-wave registers.
__global__ __launch_bounds__(1024) void k1_qkv(const float* __restrict__ x,
                                               const float* __restrict__ Wqkv,
                                               unsigned short* __restrict__ qsm,
                                               float* __restrict__ ctx_part,
                                               float* __restrict__ S_part) {
    __shared__ __align__(16) unsigned short xs0[64 * 136];   // [n][c], stride 136 (dbuf A)
    __shared__ __align__(16) unsigned short xs1[64 * 136];   // dbuf B
    __shared__ __align__(16) unsigned short ek[128 * 72];    // [h*32+d][n], stride 72
    __shared__ __align__(16) unsigned short vsh[128 * 72];   // [h*32+e][n]

    const int b    = blockIdx.y;
    const int tblk = blockIdx.x;                 // 0..7
    const int tid  = threadIdx.x;

    const int lane = tid & 63;
    const int wv   = tid >> 6;                   // 0..15
    const int l15  = lane & 15;
    const int quad = lane >> 4;

    const float4v zero = {0.f, 0.f, 0.f, 0.f};

    // --- persistent wq fragments: f32 load + RNE convert, once per block ---
    short8 wfa[8];                               // [half(0: rows +0..15, 1: +16..31)*4 + kk]
    if (wv < 12) {
        const float* wqp = Wqkv + (wv * 32 + l15) * C_ + quad * 8;
        #pragma unroll
        for (int kk = 0; kk < 4; kk++) {
            float4v a0 = *(const float4v*)(wqp + kk * 32);
            float4v a1 = *(const float4v*)(wqp + kk * 32 + 4);
            float4v b0 = *(const float4v*)(wqp + 16 * C_ + kk * 32);
            float4v b1 = *(const float4v*)(wqp + 16 * C_ + kk * 32 + 4);
            short8 lo, hi;
            #pragma unroll
            for (int j = 0; j < 4; j++) {
                lo[j]     = (short)bf16_rne(a0[j]);
                lo[4 + j] = (short)bf16_rne(a1[j]);
                hi[j]     = (short)bf16_rne(b0[j]);
                hi[4 + j] = (short)bf16_rne(b1[j]);
            }
            wfa[kk]     = lo;
            wfa[4 + kk] = hi;
        }
    }

    // --- staging lanes (waves 12-15): 256 threads, each 32 c-rows of one n ---
    const int sid = tid & 255;                   // for wv>=12: 0..255
    const int snl = sid & 63;                    // n within subtile
    const int scg = sid >> 6;                    // c group of 32
    const float* xbase = x + ((size_t)b * C_ + (size_t)scg * 32) * N_ + snl;
    float xv[32];                                // raw loads (issued one phase early)
    short8 c16[4];                               // converted subtile, write-late
    auto load_x = [&](int s) {
        const float* xp = xbase + (tblk * NSUB + s) * 64;
        #pragma unroll
        for (int i = 0; i < 32; i++) xv[i] = xp[(size_t)i * N_];
    };
    auto conv_x = [&]() {
        #pragma unroll
        for (int ii = 0; ii < 4; ii++) {
            short8 v8;
            #pragma unroll
            for (int j = 0; j < 8; j++) v8[j] = (short)bf16_rne(xv[ii * 8 + j]);
            c16[ii] = v8;
        }
    };
    auto store_c = [&](unsigned short* xs) {
        unsigned short* dst = &xs[snl * 136 + scg * 32];
        #pragma unroll
        for (int ii = 0; ii < 4; ii++) *(short8*)(dst + ii * 8) = c16[ii];
    };

    if (wv >= 12) {
        load_x(0); conv_x(); store_c(xs0);       // subtile 0 staged
        load_x(1);                               // subtile 1 loads in flight into phase 0
    }
    unsigned short* xs_cur = xs0;
    unsigned short* xs_nxt = xs1;

    float4v cacc = zero;                         // this wave's single ctx tile
    float sk0[4] = {0.f, 0.f, 0.f, 0.f};         // S partial accum (k waves only)
    float sk1[4] = {0.f, 0.f, 0.f, 0.f};
    const int ch  = wv >> 2;                     // ctx tile coords (valid for all 16 wv)
    const int cdt = (wv >> 1) & 1;
    const int cet = wv & 1;

    for (int s = 0; s < NSUB; s++) {
        const int ns = (tblk * NSUB + s) * 64;
        __syncthreads();                         // A: xs_cur staged; ek/vsh free

        if (wv < 12) {
            #pragma unroll
            for (int ct = 0; ct < 4; ct++) {
                short8 bfx[4];
                #pragma unroll
                for (int kk = 0; kk < 4; kk++)
                    bfx[kk] = *(const short8*)&xs_cur[(ct * 16 + l15) * 136 + kk * 32 + quad * 8];
                float4v acc0 = zero, acc1 = zero;
                #pragma unroll
                for (int kk = 0; kk < 4; kk++) {
                    acc0 = __builtin_amdgcn_mfma_f32_16x16x32_bf16(wfa[kk],     bfx[kk], acc0, 0, 0, 0);
                    acc1 = __builtin_amdgcn_mfma_f32_16x16x32_bf16(wfa[4 + kk], bfx[kk], acc1, 0, 0, 0);
                }
                const int ncol = ct * 16 + l15;
                // C/D layout: col = l15, row = quad*4 + r (acc0: rows 0-15, acc1: 16-31)
                if (wv < 4) {                    // q, head h = wv: softmax over d per column
                    float e0[4], e1[4], z = 0.f;
                    #pragma unroll
                    for (int r = 0; r < 4; r++) {
                        e0[r] = __expf(acc0[r]); e1[r] = __expf(acc1[r]);
                        z += e0[r] + e1[r];
                    }
                    z += __shfl_xor(z, 16, 64);
                    z += __shfl_xor(z, 32, 64);
                    const float iz = 1.0f / z;
                    unsigned short* qp = qsm + ((size_t)b * N_ + ns + ncol) * C_ + wv * 32 + quad * 4;
                    short4v s0, s1;
                    #pragma unroll
                    for (int r = 0; r < 4; r++) {
                        s0[r] = (short)bf16_rne(e0[r] * iz);
                        s1[r] = (short)bf16_rne(e1[r] * iz);
                    }
                    *(short4v*)qp = s0;          // d = quad*4..+3
                    *(short4v*)(qp + 16) = s1;   // d = 16+quad*4..+3
                } else if (wv < 8) {             // k, head h = wv-4: exp -> LDS + S accum
                    const int row0 = (wv - 4) * 32 + quad * 4;
                    #pragma unroll
                    for (int r = 0; r < 4; r++) {
                        const float e0v = __expf(acc0[r]);
                        const float e1v = __expf(acc1[r]);
                        sk0[r] += e0v;
                        sk1[r] += e1v;
                        ek[(row0 + r) * 72 + ncol]      = bf16_rne(e0v);
                        ek[(row0 + 16 + r) * 72 + ncol] = bf16_rne(e1v);
                    }
                } else {                         // v, head h = wv-8 -> LDS
                    const int row0 = (wv - 8) * 32 + quad * 4;
                    #pragma unroll
                    for (int r = 0; r < 4; r++) {
                        vsh[(row0 + r) * 72 + ncol]      = bf16_rne(acc0[r]);
                        vsh[(row0 + 16 + r) * 72 + ncol] = bf16_rne(acc1[r]);
                    }
                }
            }
        } else {
            if (s + 1 < NSUB) { conv_x(); store_c(xs_nxt); }  // loads from phase s-1
            if (s + 2 < NSUB) load_x(s + 2);                  // issue only; consumed next phase
        }
        __syncthreads();                         // B: ek/vsh ready; xs_nxt staged

        // context: cacc[d][e] += sum_n expk[d][n] * v[e][n]  (one 16x16 tile per wave)
        {
            const unsigned short* ap = &ek[(ch * 32 + cdt * 16 + l15) * 72 + quad * 8];
            const unsigned short* bp = &vsh[(ch * 32 + cet * 16 + l15) * 72 + quad * 8];
            #pragma unroll
            for (int kk = 0; kk < 2; kk++) {
                short8 a  = *(const short8*)(ap + kk * 32);
                short8 bb = *(const short8*)(bp + kk * 32);
                cacc = __builtin_amdgcn_mfma_f32_16x16x32_bf16(a, bb, cacc, 0, 0, 0);
            }
        }
        { unsigned short* t = xs_cur; xs_cur = xs_nxt; xs_nxt = t; }
    }

    // write-out: plain stores, no atomics
    {
        float* cp = ctx_part + ((size_t)(b * TPB_ + tblk) << 12)
                  + ((ch * 32 + cdt * 16 + quad * 4) * 32 + cet * 16 + l15);
        #pragma unroll
        for (int r = 0; r < 4; r++) cp[r * 32] = cacc[r];
    }
    // S: k-waves reduce their register partials over the 16-lane column group
    if (wv >= 4 && wv < 8) {
        const int srow = (wv - 4) * 32 + quad * 4;
        float* sp = S_part + (size_t)(b * TPB_ + tblk) * 128;
        #pragma unroll
        for (int r = 0; r < 4; r++) {
            float a0 = sk0[r], a1 = sk1[r];
            a0 += __shfl_xor(a0, 1, 64); a0 += __shfl_xor(a0, 2, 64);
            a0 += __shfl_xor(a0, 4, 64); a0 += __shfl_xor(a0, 8, 64);
            a1 += __shfl_xor(a1, 1, 64); a1 += __shfl_xor(a1, 2, 64);
            a1 += __shfl_xor(a1, 4, 64); a1 += __shfl_xor(a1, 8, 64);
            if (l15 == 0) { sp[srow + r] = a0; sp[srow + 16 + r] = a1; }
        }
    }
}

// K2 (fused R14): one block per batch, 512 thr.
// Phase 1: Sinv[128]. Phase 2: reduce 8 ctx partials, *Sinv, bf16 -> LDS ctxb
// [128][40] (stride-40 shorts: 16B-aligned b128 reads — R6-proven). Phase 3:
// Wbig[o][hd] = sum_e Wout[o][h*32+e] * ctxN[hd][e] via 8 MFMAs/wave, Wout frags
// converted f32->bf16 in registers; written FRAG-MAJOR (chunk c = (o>>4)*4+(hd>>5))
// so k3 stages linearly and reads lane-contiguous ds_read_b128.
__global__ __launch_bounds__(512) void k2_fused(const float* __restrict__ ctx_part,
                                                const float* __restrict__ S_part,
                                                const float* __restrict__ Wout,
                                                unsigned short* __restrict__ wbig) {
    __shared__ float Sinv[128];
    __shared__ __align__(16) unsigned short ctxb[128 * 40];  // [h*32+d][e]
    const int b   = blockIdx.x;
    const int tid = threadIdx.x;

    if (tid < 128) {
        float s = 0.f;
        #pragma unroll
        for (int t = 0; t < TPB_; t++)
            s += S_part[(size_t)(b * TPB_ + t) * 128 + tid];
        Sinv[tid] = 1.0f / s;
    }
    __syncthreads();

    #pragma unroll
    for (int i = 0; i < 8; i++) {
        const int ei = i * 512 + tid;            // flat [hd][e]
        float v = 0.f;
        #pragma unroll
        for (int t = 0; t < TPB_; t++)
            v += ctx_part[((size_t)(b * TPB_ + t) << 12) + ei];
        ctxb[(ei >> 5) * 40 + (ei & 31)] = bf16_rne(v * Sinv[ei >> 5]);
    }
    __syncthreads();

    const int lane = tid & 63, wv = tid >> 6, l15 = lane & 15, quad = lane >> 4;
    const float4v zero = {0.f, 0.f, 0.f, 0.f};

    short8 a4[4];                                // Wout frags, f32 load + RNE convert
    {
        const float* wop = Wout + (wv * 16 + l15) * C_ + quad * 8;
        #pragma unroll
        for (int h = 0; h < 4; h++) {
            float4v f0 = *(const float4v*)(wop + h * 32);
            float4v f1 = *(const float4v*)(wop + h * 32 + 4);
            short8 w;
            #pragma unroll
            for (int j = 0; j < 4; j++) {
                w[j]     = (short)bf16_rne(f0[j]);
                w[4 + j] = (short)bf16_rne(f1[j]);
            }
            a4[h] = w;
        }
    }

    unsigned short* wb = wbig + (size_t)b * (C_ * C_);
    #pragma unroll
    for (int ht = 0; ht < 8; ht++) {             // hd-tile: head ht>>1, d-half ht&1
        const int h_ = ht >> 1;
        short8 bb = *(const short8*)&ctxb[(h_ * 32 + (ht & 1) * 16 + l15) * 40 + quad * 8];
        float4v c4 = __builtin_amdgcn_mfma_f32_16x16x32_bf16(a4[h_], bb, zero, 0, 0, 0);
        // value (r): o = wv*16+quad*4+r, hd = ht*16+l15
        const int c     = wv * 4 + (ht >> 1);
        const int quadp = (ht & 1) * 2 + (l15 >> 3);
        #pragma unroll
        for (int r = 0; r < 4; r++)
            wb[((c * 64 + quadp * 16 + quad * 4 + r) << 3) + (l15 & 7)] = bf16_rne(c4[r]);
    }
}

// K3: grid-stride persistent y = Wbig[b] @ qsm + bout, LayerNorm over c.
// 512 blocks (2/CU) x 512 thr; each block owns 256 n-cols = 2 tiles of 128.
// wbig (32KB frag-major) + bout/lnw/lnb staged into LDS ONCE per block; per tile the
// next tile's qsm frags are prefetched before the MFMA+store phase. One barrier total.
__global__ __launch_bounds__(512) void k3_out(const unsigned short* __restrict__ qsm,
                                              const unsigned short* __restrict__ wbig,
                                              const float* __restrict__ bout,
                                              const float* __restrict__ lnw,
                                              const float* __restrict__ lnb,
                                              float* __restrict__ out) {
    __shared__ __align__(16) unsigned short wls[16384];      // 32KB
    __shared__ float lnp[384];                               // bout | lnw | lnb

    const int b    = blockIdx.y;
    const int tseg = blockIdx.x;                 // 0..15: n-cols tseg*256 .. +255
    const int tid  = threadIdx.x;

    const int lane = tid & 63, wv = tid >> 6, l15 = lane & 15, quad = lane >> 4;
    const int nl = wv * 16 + l15;                // 0..127 within tile

    const float4v zero = {0.f, 0.f, 0.f, 0.f};
    const size_t n0base = (size_t)tseg * 256;

    // stage Wbig[b] 32KB -> LDS (linear: thread t copies 16B chunks t, t+512, ...)
    short8 st[4];
    {
        const short8* src = (const short8*)(wbig + (size_t)b * (C_ * C_));
        #pragma unroll
        for (int i = 0; i < 4; i++) st[i] = src[i * 512 + tid];
    }
    if (tid < 128) {
        lnp[tid]       = bout[tid];
        lnp[128 + tid] = lnw[tid];
        lnp[256 + tid] = lnb[tid];
    }
    // first tile's qsm B-frags (independent; overlap the stage)
    short8 bq[4], bqn[4];
    {
        const unsigned short* qp = qsm + ((size_t)b * N_ + n0base + nl) * C_ + quad * 8;
        #pragma unroll
        for (int kk = 0; kk < 4; kk++) bq[kk] = *(const short8*)(qp + kk * 32);
    }
    #pragma unroll
    for (int i = 0; i < 4; i++)
        *(short8*)&wls[(i * 512 + tid) * 8] = st[i];
    __syncthreads();

    #pragma unroll
    for (int t = 0; t < 2; t++) {
        const size_t n = n0base + t * 128 + nl;
        if (t == 0) {                            // prefetch next tile's frags
            const unsigned short* qp = qsm + ((size_t)b * N_ + n0base + 128 + nl) * C_ + quad * 8;
            #pragma unroll
            for (int kk = 0; kk < 4; kk++) bqn[kk] = *(const short8*)(qp + kk * 32);
        }

        float4v acc[8];
        #pragma unroll
        for (int ot = 0; ot < 8; ot++) {
            float4v a = zero;
            #pragma unroll
            for (int kk = 0; kk < 4; kk++) {
                short8 w = *(const short8*)&wls[((ot * 4 + kk) * 64 + lane) * 8];
                a = __builtin_amdgcn_mfma_f32_16x16x32_bf16(w, bq[kk], a, 0, 0, 0);
            }
            acc[ot] = a;
        }

        // bias + LayerNorm over the 128 channels of this column
        float sum = 0.f, sq = 0.f;
        #pragma unroll
        for (int ot = 0; ot < 8; ot++) {
            #pragma unroll
            for (int r = 0; r < 4; r++) {
                const int o = ot * 16 + quad * 4 + r;
                const float y = acc[ot][r] + lnp[o];
                acc[ot][r] = y;
                sum += y; sq += y * y;
            }
        }
        sum += __shfl_xor(sum, 16, 64);
        sum += __shfl_xor(sum, 32, 64);
        sq  += __shfl_xor(sq, 16, 64);
        sq  += __shfl_xor(sq, 32, 64);
        const float mean = sum * (1.0f / 128.0f);
        const float var  = sq * (1.0f / 128.0f) - mean * mean;   // biased, matches jnp.var
        const float rstd = rsqrtf(var + 1e-5f);

        #pragma unroll
        for (int ot = 0; ot < 8; ot++) {
            #pragma unroll
            for (int r = 0; r < 4; r++) {
                const int o = ot * 16 + quad * 4 + r;
                out[((size_t)b * C_ + o) * N_ + n] = (acc[ot][r] - mean) * rstd * lnp[128 + o] + lnp[256 + o];
            }
        }

        #pragma unroll
        for (int kk = 0; kk < 4; kk++) bq[kk] = bqn[kk];
    }
}

extern "C" void kernel_launch(void* const* d_in, const int* in_sizes, int n_in,
                              void* d_out, int out_size, void* d_ws, size_t ws_size,
                              hipStream_t stream) {
    const float* x    = (const float*)d_in[0];
    const float* Wqkv = (const float*)d_in[1];
    const float* Wout = (const float*)d_in[2];
    const float* bout = (const float*)d_in[3];
    const float* lnw  = (const float*)d_in[4];
    const float* lnb  = (const float*)d_in[5];
    float* out = (float*)d_out;

    char* ws = (char*)d_ws;
    float* S_part        = (float*)(ws + OFF_SP);
    float* ctx_part      = (float*)(ws + OFF_CTXP);
    unsigned short* wbig = (unsigned short*)(ws + OFF_WBIG);
    unsigned short* qsm  = (unsigned short*)(ws + OFF_QSM);

    k1_qkv<<<dim3(TPB_, B_), 1024, 0, stream>>>(x, Wqkv, qsm, ctx_part, S_part);
    k2_fused<<<B_, 512, 0, stream>>>(ctx_part, S_part, Wout, wbig);
    k3_out<<<dim3(16, B_), 512, 0, stream>>>(qsm, wbig, bout, lnw, lnb, out);
}